// Round 13
// baseline (175.924 us; speedup 1.0000x reference)
//
#include <hip/hip_runtime.h>
#include <hip/hip_bf16.h>
#include <stdint.h>

typedef float f32x4 __attribute__((ext_vector_type(4)));
typedef __bf16 bf16x8 __attribute__((ext_vector_type(8)));
typedef unsigned short u16;

#define MFMA16(a, b, c) __builtin_amdgcn_mfma_f32_16x16x32_bf16((a), (b), (c), 0, 0, 0)

__device__ __forceinline__ u16 f2bf(float f) {
  union { float f; uint32_t u; } v; v.f = f;
  uint32_t u = v.u;
  return (u16)((u + 0x7fffu + ((u >> 16) & 1u)) >> 16);
}
__device__ __forceinline__ float bf2f(u16 h) {
  union { uint32_t u; float f; } v; v.u = ((uint32_t)h) << 16;
  return v.f;
}

// ---------------- kernel 0: weights -> bf16 transposed [c][k] -----------------
__global__ void prep_weights_kernel(const float* __restrict__ Wq, const float* __restrict__ Wk,
                                    const float* __restrict__ Wv, const float* __restrict__ Wp,
                                    u16* __restrict__ Wt) {
  int w = blockIdx.x;
  const float* W = (w == 0) ? Wq : (w == 1) ? Wk : (w == 2) ? Wv : Wp;
  int t = blockIdx.y * 256 + threadIdx.x;  // 0..16383
  int c = t >> 7, k = t & 127;
  Wt[(w * 128 + c) * 128 + k] = f2bf(W[k * 128 + c]);
}

// ---------------- FUSED kernel v2: 16 waves (4/SIMD), coalesced store --------
// 400 blocks x 1024 threads, wave = 16 q-rows. Same dataflow as fused v1
// (x staged once; K overwrites own x rows; V^T; in-block vmean; fixed-max
// softmax attention; out-proj + LN) but at 2x waves/SIMD to halve latency
// exposure of the QKV-GEMM and staging sections, and with the epilogue
// restructured: y (bf16) parked in the dead KX buffer after a barrier, then
// block-cooperatively streamed out with 32 lanes/row = full 512B segments.
__global__ __launch_bounds__(1024, 1) void fused2_kernel(
    const u16* __restrict__ Wt, const float* __restrict__ x,
    const int* __restrict__ mask, const float* __restrict__ rel,
    const float* __restrict__ bq, const float* __restrict__ bk,
    const float* __restrict__ bv, const float* __restrict__ bp,
    const float* __restrict__ ln_g, const float* __restrict__ ln_b,
    float* __restrict__ out) {
  __shared__ u16 KX[256][136];        // x (phase A) -> K (phase B) -> y (epi)  69632 B
  __shared__ u16 V_lds[128][264];     // V^T [d][t]                             67584 B
  __shared__ u16 P_lds[16][16][40];   // per-wave repack slices                 20480 B
  __shared__ float rel_lds[511];      //                                         2044 B
  __shared__ float vmean_lds[128];    //                                          512 B -> 160252 B
  const int tid = threadIdx.x;
  const int n = blockIdx.x;
  const int bb = n / 100, rr = n - bb * 100;
  const int* mrow = mask + bb * 256;
  if (tid < 511) rel_lds[tid] = rel[tid];
  {  // stage x[n] -> KX as bf16 (contiguous 131 KB read, 1024 threads)
    int row = tid >> 2, seg = (tid & 3) * 32;
    const float* src = x + ((size_t)(n * 256 + row)) * 128 + seg;
    u16* dst = &KX[row][seg];
#pragma unroll
    for (int j = 0; j < 8; ++j) {
      float4 f = ((const float4*)src)[j];
      dst[j * 4 + 0] = f2bf(f.x); dst[j * 4 + 1] = f2bf(f.y);
      dst[j * 4 + 2] = f2bf(f.z); dst[j * 4 + 3] = f2bf(f.w);
    }
  }
  const int l = tid & 63, wv = tid >> 6, l15 = l & 15, l4 = l >> 4;
  const int tt0 = wv * 16;  // this wave's 16 q-rows
  int ttg[4], qm[4];
#pragma unroll
  for (int rg = 0; rg < 4; ++rg) { ttg[rg] = tt0 + 4 * l4 + rg; qm[rg] = mrow[tt0 + 4 * l4 + rg]; }
  __syncthreads();  // barrier 1: x + rel staged

  // ---- own x rows: A-frags + packed residual ----
  bf16x8 af[4];
#pragma unroll
  for (int ks = 0; ks < 4; ++ks)
    af[ks] = *(const bf16x8*)&KX[tt0 + l15][ks * 32 + l4 * 8];
  uint32_t xres[4][4];
#pragma unroll
  for (int rg = 0; rg < 4; ++rg) {
    const u16* xr = &KX[tt0 + 4 * l4 + rg][0];
#pragma unroll
    for (int c = 0; c < 4; ++c)
      xres[rg][c] = (uint32_t)xr[c * 32 + l15] | ((uint32_t)xr[c * 32 + 16 + l15] << 16);
  }

  const float scale = 0.088388347648318447f;  // 1/sqrt(128)
  f32x4 acc[8];
  // ---- Q = x @ Wq + bq -> qa[] via P-slice repack ----
#pragma unroll
  for (int ct = 0; ct < 8; ++ct) acc[ct] = f32x4{0.f, 0.f, 0.f, 0.f};
#pragma unroll
  for (int ct = 0; ct < 8; ++ct)
#pragma unroll
    for (int ks = 0; ks < 4; ++ks) {
      bf16x8 wb = *(const bf16x8*)(Wt + (size_t)(0 * 128 + ct * 16 + l15) * 128 + ks * 32 + l4 * 8);
      acc[ct] = MFMA16(af[ks], wb, acc[ct]);
    }
  bf16x8 qa[4];
#pragma unroll
  for (int ks = 0; ks < 4; ++ks) {
#pragma unroll
    for (int c2 = 0; c2 < 2; ++c2) {
      int ct = ks * 2 + c2;
      float bqv = bq[ct * 16 + l15];
#pragma unroll
      for (int rg = 0; rg < 4; ++rg)
        P_lds[wv][4 * l4 + rg][c2 * 16 + l15] = f2bf((acc[ct][rg] + bqv) * scale);
    }
    qa[ks] = *(const bf16x8*)&P_lds[wv][l15][l4 * 8];
  }
  // ---- K = x @ Wk + bk -> overwrite OWN x rows in KX ----
#pragma unroll
  for (int ct = 0; ct < 8; ++ct) acc[ct] = f32x4{0.f, 0.f, 0.f, 0.f};
#pragma unroll
  for (int ct = 0; ct < 8; ++ct)
#pragma unroll
    for (int ks = 0; ks < 4; ++ks) {
      bf16x8 wb = *(const bf16x8*)(Wt + (size_t)(1 * 128 + ct * 16 + l15) * 128 + ks * 32 + l4 * 8);
      acc[ct] = MFMA16(af[ks], wb, acc[ct]);
    }
#pragma unroll
  for (int ct = 0; ct < 8; ++ct) {
    float bkv = bk[ct * 16 + l15];
#pragma unroll
    for (int rg = 0; rg < 4; ++rg)
      KX[tt0 + 4 * l4 + rg][ct * 16 + l15] = f2bf(acc[ct][rg] + bkv);
  }
  // ---- V = x @ Wv + bv -> V^T region ----
#pragma unroll
  for (int ct = 0; ct < 8; ++ct) acc[ct] = f32x4{0.f, 0.f, 0.f, 0.f};
#pragma unroll
  for (int ct = 0; ct < 8; ++ct)
#pragma unroll
    for (int ks = 0; ks < 4; ++ks) {
      bf16x8 wb = *(const bf16x8*)(Wt + (size_t)(2 * 128 + ct * 16 + l15) * 128 + ks * 32 + l4 * 8);
      acc[ct] = MFMA16(af[ks], wb, acc[ct]);
    }
#pragma unroll
  for (int ct = 0; ct < 8; ++ct) {
    float bvv = bv[ct * 16 + l15];
#pragma unroll
    for (int rg = 0; rg < 4; ++rg)
      V_lds[ct * 16 + l15][tt0 + 4 * l4 + rg] = f2bf(acc[ct][rg] + bvv);
  }
  __syncthreads();  // barrier 2: K/V complete
  {  // in-block vmean over V^T rows (1024 thr: 8 lanes per d)
    int d = tid >> 3, seg = tid & 7;
    const u16* vr = &V_lds[d][seg * 32];
    float s = 0.f;
#pragma unroll
    for (int j = 0; j < 4; ++j) {
      uint4 u = *(const uint4*)(vr + j * 8);
      s += bf2f((u16)(u.x & 0xffff)) + bf2f((u16)(u.x >> 16));
      s += bf2f((u16)(u.y & 0xffff)) + bf2f((u16)(u.y >> 16));
      s += bf2f((u16)(u.z & 0xffff)) + bf2f((u16)(u.z >> 16));
      s += bf2f((u16)(u.w & 0xffff)) + bf2f((u16)(u.w >> 16));
    }
    s += __shfl_xor(s, 1); s += __shfl_xor(s, 2); s += __shfl_xor(s, 4);
    if (seg == 0) vmean_lds[d] = s * (1.f / 256.f);
  }
  float lsum[4]; f32x4 cacc[8];
#pragma unroll
  for (int rg = 0; rg < 4; ++rg) lsum[rg] = 0.f;
#pragma unroll
  for (int ct = 0; ct < 8; ++ct) cacc[ct] = f32x4{0.f, 0.f, 0.f, 0.f};
  __syncthreads();  // barrier 3: vmean ready

  // ---- attention: fixed-max softmax, 16 rows/wave ----
  const int nkv = (wv >> 2) + 1;
  for (int kv = 0; kv < nkv; ++kv) {
    const int s0 = kv * 64;
    f32x4 sacc[4];
#pragma unroll
    for (int ct = 0; ct < 4; ++ct) sacc[ct] = f32x4{0.f, 0.f, 0.f, 0.f};
#pragma unroll
    for (int ct = 0; ct < 4; ++ct)
#pragma unroll
      for (int ks = 0; ks < 4; ++ks) {
        bf16x8 bfr = *(const bf16x8*)&KX[s0 + ct * 16 + l15][ks * 32 + l4 * 8];
        sacc[ct] = MFMA16(qa[ks], bfr, sacc[ct]);
      }
    int km[4];
#pragma unroll
    for (int ct = 0; ct < 4; ++ct) km[ct] = mrow[s0 + ct * 16 + l15];
    float p[4][4];
#pragma unroll
    for (int ct = 0; ct < 4; ++ct) {
      const int ss = s0 + ct * 16 + l15;
#pragma unroll
      for (int rg = 0; rg < 4; ++rg) {
        float sv = sacc[ct][rg] + rel_lds[ttg[rg] - ss + 255];
        bool msk = (ss > ttg[rg]) | (km[ct] == 0) | (qm[rg] == 0);
        sv = msk ? -1.0e9f : sv;
        float pv = __expf(sv);  // masked -> exactly 0
        p[ct][rg] = pv;
        lsum[rg] += pv;
      }
    }
#pragma unroll
    for (int c = 0; c < 2; ++c) {
#pragma unroll
      for (int c2 = 0; c2 < 2; ++c2)
#pragma unroll
        for (int rg = 0; rg < 4; ++rg)
          P_lds[wv][4 * l4 + rg][c2 * 16 + l15] = f2bf(p[2 * c + c2][rg]);
      bf16x8 pa = *(const bf16x8*)&P_lds[wv][l15][l4 * 8];
#pragma unroll
      for (int ct = 0; ct < 8; ++ct) {
        bf16x8 vb = *(const bf16x8*)&V_lds[ct * 16 + l15][s0 + c * 32 + l4 * 8];
        cacc[ct] = MFMA16(pa, vb, cacc[ct]);
      }
    }
  }
  float li[4];
#pragma unroll
  for (int rg = 0; rg < 4; ++rg) {
    float rs = lsum[rg];
#pragma unroll
    for (int off = 1; off < 16; off <<= 1) rs += __shfl_xor(rs, off);
    li[rg] = rs;
  }
  // ---- ctx -> out-proj ----
  bf16x8 ca[4];
#pragma unroll
  for (int q = 0; q < 4; ++q) {
#pragma unroll
    for (int c2 = 0; c2 < 2; ++c2) {
      int ct = 2 * q + c2;
      float vm = vmean_lds[ct * 16 + l15];
#pragma unroll
      for (int rg = 0; rg < 4; ++rg) {
        float cval = cacc[ct][rg] / li[rg];
        cval = (qm[rg] == 0) ? vm : cval;
        P_lds[wv][4 * l4 + rg][c2 * 16 + l15] = f2bf(cval);
      }
    }
    ca[q] = *(const bf16x8*)&P_lds[wv][l15][l4 * 8];
  }
  f32x4 oacc[8];
#pragma unroll
  for (int ct = 0; ct < 8; ++ct) oacc[ct] = f32x4{0.f, 0.f, 0.f, 0.f};
#pragma unroll
  for (int ct = 0; ct < 8; ++ct)
#pragma unroll
    for (int ks = 0; ks < 4; ++ks) {
      bf16x8 wb = *(const bf16x8*)(Wt + (size_t)(3 * 128 + ct * 16 + l15) * 128 + ks * 32 + l4 * 8);
      oacc[ct] = MFMA16(ca[ks], wb, oacc[ct]);
    }
  // ---- residual + LN -> y (bf16) parked in KX after all attn reads done ----
  float bpv[8], gv[8], bt[8];
#pragma unroll
  for (int ct = 0; ct < 8; ++ct) {
    int d = ct * 16 + l15;
    bpv[ct] = bp[d]; gv[ct] = ln_g[d]; bt[ct] = ln_b[d];
  }
  float yout[4][8];
#pragma unroll
  for (int rg = 0; rg < 4; ++rg) {
    float yv[8], sum = 0.f, sq = 0.f;
#pragma unroll
    for (int ct = 0; ct < 8; ++ct) {
      uint32_t pr = xres[rg][ct >> 1];
      u16 xh = (ct & 1) ? (u16)(pr >> 16) : (u16)(pr & 0xffff);
      float v = oacc[ct][rg] + bpv[ct] + bf2f(xh);
      yv[ct] = v; sum += v; sq += v * v;
    }
#pragma unroll
    for (int off = 1; off < 16; off <<= 1) { sum += __shfl_xor(sum, off); sq += __shfl_xor(sq, off); }
    float mean = sum * (1.f / 128.f);
    float var = sq * (1.f / 128.f) - mean * mean;
    float rstd = rsqrtf(var + 1e-5f);
#pragma unroll
    for (int ct = 0; ct < 8; ++ct) yout[rg][ct] = (yv[ct] - mean) * rstd * gv[ct] + bt[ct];
  }
  __syncthreads();  // barrier 4: all waves done reading KX (K) and V
#pragma unroll
  for (int rg = 0; rg < 4; ++rg)
#pragma unroll
    for (int ct = 0; ct < 8; ++ct)
      KX[ttg[rg]][ct * 16 + l15] = f2bf(yout[rg][ct]);
  __syncthreads();  // barrier 5: y complete
  // ---- cooperative coalesced store: 32 lanes per row = full 512B segments ----
  {
    int lane32 = tid & 31, rbase = tid >> 5;  // 32 rows per pass
#pragma unroll
    for (int pass = 0; pass < 8; ++pass) {
      int row = rbase + pass * 32;
      const u16* yr = &KX[row][lane32 * 4];
      float4 f;
      f.x = bf2f(yr[0]); f.y = bf2f(yr[1]); f.z = bf2f(yr[2]); f.w = bf2f(yr[3]);
      float* orow = out + (((size_t)(bb * 256 + row)) * 100 + rr) * 128 + lane32 * 4;
      *(float4*)orow = f;
    }
  }
}

extern "C" void kernel_launch(void* const* d_in, const int* in_sizes, int n_in,
                              void* d_out, int out_size, void* d_ws, size_t ws_size,
                              hipStream_t stream) {
  const float* x    = (const float*)d_in[0];
  const int*   mask = (const int*)d_in[1];
  const float* Wq   = (const float*)d_in[2];
  const float* bq   = (const float*)d_in[3];
  const float* Wk   = (const float*)d_in[4];
  const float* bk   = (const float*)d_in[5];
  const float* Wv   = (const float*)d_in[6];
  const float* bv   = (const float*)d_in[7];
  const float* Wp   = (const float*)d_in[8];
  const float* bp   = (const float*)d_in[9];
  const float* ln_g = (const float*)d_in[10];
  const float* ln_b = (const float*)d_in[11];
  const float* rel  = (const float*)d_in[12];
  float* out = (float*)d_out;
  u16* Wt = (u16*)d_ws;  // [4][128][128] bf16 transposed — only workspace use

  hipLaunchKernelGGL(prep_weights_kernel, dim3(4, 64), dim3(256), 0, stream, Wq, Wk, Wv, Wp, Wt);
  hipLaunchKernelGGL(fused2_kernel, dim3(400), dim3(1024), 0, stream,
                     Wt, x, mask, rel, bq, bk, bv, bp, ln_g, ln_b, out);
}

// Round 14
// 110.390 us; speedup vs baseline: 1.5937x; 1.5937x over previous
//
#include <hip/hip_runtime.h>
#include <hip/hip_bf16.h>
#include <stdint.h>

typedef float f32x4 __attribute__((ext_vector_type(4)));
typedef __bf16 bf16x8 __attribute__((ext_vector_type(8)));
typedef unsigned short u16;

#define MFMA16(a, b, c) __builtin_amdgcn_mfma_f32_16x16x32_bf16((a), (b), (c), 0, 0, 0)

__device__ __forceinline__ u16 f2bf(float f) {
  union { float f; uint32_t u; } v; v.f = f;
  uint32_t u = v.u;
  return (u16)((u + 0x7fffu + ((u >> 16) & 1u)) >> 16);
}
__device__ __forceinline__ float bf2f(u16 h) {
  union { uint32_t u; float f; } v; v.u = ((uint32_t)h) << 16;
  return v.f;
}

// ---------------- kernel 0: weights -> bf16 transposed [c][k] -----------------
__global__ void prep_weights_kernel(const float* __restrict__ Wq, const float* __restrict__ Wk,
                                    const float* __restrict__ Wv, const float* __restrict__ Wp,
                                    u16* __restrict__ Wt) {
  int w = blockIdx.x;
  const float* W = (w == 0) ? Wq : (w == 1) ? Wk : (w == 2) ? Wv : Wp;
  int t = blockIdx.y * 256 + threadIdx.x;  // 0..16383
  int c = t >> 7, k = t & 127;
  Wt[(w * 128 + c) * 128 + k] = f2bf(W[k * 128 + c]);
}

// ---------------- FUSED kernel v3: fused1 + WAVE-PRIVATE staging -------------
// 400 blocks x 512 threads (8 waves, 32 q-rows each — keeps the g={0,1}
// weight-fragment sharing fused2 lost). Change vs fused1 (123us): each wave
// stages only its OWN 32 x-rows (16 KB, coalesced) into its own KX region and
// barrier-1 is DELETED — waves flow independently through stage->Q->K->V until
// barrier-2. Epilogue is fused1's verified scatter (fused2's "coalesced" store
// inflated WRITE_SIZE 58->94 MB and is reverted).
__global__ __launch_bounds__(512, 1) void fused3_kernel(
    const u16* __restrict__ Wt, const float* __restrict__ x,
    const int* __restrict__ mask, const float* __restrict__ rel,
    const float* __restrict__ bq, const float* __restrict__ bk,
    const float* __restrict__ bv, const float* __restrict__ bp,
    const float* __restrict__ ln_g, const float* __restrict__ ln_b,
    float* __restrict__ out) {
  __shared__ u16 KX[256][136];        // x (per-wave) -> K               69632 B
  __shared__ u16 V_lds[128][264];     // V^T [d][t]                      67584 B
  __shared__ u16 P_lds[8][32][40];    // per-wave repack slices          20480 B
  __shared__ float rel_lds[511];      //                                  2044 B
  __shared__ float vmean_lds[128];    //                                   512 B -> 160252 B
  const int tid = threadIdx.x;
  const int n = blockIdx.x;
  const int bb = n / 100, rr = n - bb * 100;
  const int* mrow = mask + bb * 256;
  if (tid < 511) rel_lds[tid] = rel[tid];
  const int l = tid & 63, wv = tid >> 6, l15 = l & 15, l4 = l >> 4;
  const int tt0 = wv * 32;  // this wave's 32 q-rows
  {  // WAVE-PRIVATE stage: own 32 rows of x -> KX[tt0..tt0+32) (no barrier)
    int row = tt0 + (l >> 1), half = (l & 1) * 64;
    const float* src = x + ((size_t)(n * 256 + row)) * 128 + half;
    u16* dst = &KX[row][half];
#pragma unroll
    for (int j = 0; j < 16; ++j) {
      float4 f = ((const float4*)src)[j];
      dst[j * 4 + 0] = f2bf(f.x); dst[j * 4 + 1] = f2bf(f.y);
      dst[j * 4 + 2] = f2bf(f.z); dst[j * 4 + 3] = f2bf(f.w);
    }
  }
  int ttg[2][4], qm[2][4];
#pragma unroll
  for (int g = 0; g < 2; ++g)
#pragma unroll
    for (int rg = 0; rg < 4; ++rg) {
      ttg[g][rg] = tt0 + g * 16 + 4 * l4 + rg;
      qm[g][rg] = mrow[ttg[g][rg]];
    }

  // ---- per-wave reads of OWN x rows (A-frags + packed residual) ----
  // (same-wave LDS dependency; compiler inserts lgkmcnt waits)
  bf16x8 af[2][4];
#pragma unroll
  for (int g = 0; g < 2; ++g)
#pragma unroll
    for (int ks = 0; ks < 4; ++ks)
      af[g][ks] = *(const bf16x8*)&KX[tt0 + g * 16 + l15][ks * 32 + l4 * 8];
  uint32_t xres[2][4][4];  // x[ttg[g][rg]][ct*16+l15], ct=2c|2c+1 packed
#pragma unroll
  for (int g = 0; g < 2; ++g)
#pragma unroll
    for (int rg = 0; rg < 4; ++rg) {
      const u16* xr = &KX[tt0 + g * 16 + 4 * l4 + rg][0];
#pragma unroll
      for (int c = 0; c < 4; ++c)
        xres[g][rg][c] = (uint32_t)xr[c * 32 + l15] | ((uint32_t)xr[c * 32 + 16 + l15] << 16);
    }

  const float scale = 0.088388347648318447f;  // 1/sqrt(128)
  f32x4 acc[2][8];
  // ---- Q = x @ Wq + bq (keep in regs as A-frags via P-slice repack) ----
#pragma unroll
  for (int g = 0; g < 2; ++g)
#pragma unroll
    for (int ct = 0; ct < 8; ++ct) acc[g][ct] = f32x4{0.f, 0.f, 0.f, 0.f};
#pragma unroll
  for (int ct = 0; ct < 8; ++ct)
#pragma unroll
    for (int ks = 0; ks < 4; ++ks) {
      bf16x8 wb = *(const bf16x8*)(Wt + (size_t)(0 * 128 + ct * 16 + l15) * 128 + ks * 32 + l4 * 8);
#pragma unroll
      for (int g = 0; g < 2; ++g) acc[g][ct] = MFMA16(af[g][ks], wb, acc[g][ct]);
    }
  bf16x8 qa[2][4];
#pragma unroll
  for (int ks = 0; ks < 4; ++ks) {  // repack cols [ks*32, ks*32+32) via P slice
#pragma unroll
    for (int g = 0; g < 2; ++g)
#pragma unroll
      for (int c2 = 0; c2 < 2; ++c2) {
        int ct = ks * 2 + c2;
        float bqv = bq[ct * 16 + l15];
#pragma unroll
        for (int rg = 0; rg < 4; ++rg)
          P_lds[wv][g * 16 + 4 * l4 + rg][c2 * 16 + l15] = f2bf((acc[g][ct][rg] + bqv) * scale);
      }
#pragma unroll
    for (int g = 0; g < 2; ++g)
      qa[g][ks] = *(const bf16x8*)&P_lds[wv][g * 16 + l15][l4 * 8];
  }
  // ---- K = x @ Wk + bk -> overwrite OWN x rows in KX ----
#pragma unroll
  for (int g = 0; g < 2; ++g)
#pragma unroll
    for (int ct = 0; ct < 8; ++ct) acc[g][ct] = f32x4{0.f, 0.f, 0.f, 0.f};
#pragma unroll
  for (int ct = 0; ct < 8; ++ct)
#pragma unroll
    for (int ks = 0; ks < 4; ++ks) {
      bf16x8 wb = *(const bf16x8*)(Wt + (size_t)(1 * 128 + ct * 16 + l15) * 128 + ks * 32 + l4 * 8);
#pragma unroll
      for (int g = 0; g < 2; ++g) acc[g][ct] = MFMA16(af[g][ks], wb, acc[g][ct]);
    }
#pragma unroll
  for (int ct = 0; ct < 8; ++ct) {
    float bkv = bk[ct * 16 + l15];
#pragma unroll
    for (int g = 0; g < 2; ++g)
#pragma unroll
      for (int rg = 0; rg < 4; ++rg)
        KX[tt0 + g * 16 + 4 * l4 + rg][ct * 16 + l15] = f2bf(acc[g][ct][rg] + bkv);
  }
  // ---- V = x @ Wv + bv -> V^T region (wave-private column slice) ----
#pragma unroll
  for (int g = 0; g < 2; ++g)
#pragma unroll
    for (int ct = 0; ct < 8; ++ct) acc[g][ct] = f32x4{0.f, 0.f, 0.f, 0.f};
#pragma unroll
  for (int ct = 0; ct < 8; ++ct)
#pragma unroll
    for (int ks = 0; ks < 4; ++ks) {
      bf16x8 wb = *(const bf16x8*)(Wt + (size_t)(2 * 128 + ct * 16 + l15) * 128 + ks * 32 + l4 * 8);
#pragma unroll
      for (int g = 0; g < 2; ++g) acc[g][ct] = MFMA16(af[g][ks], wb, acc[g][ct]);
    }
#pragma unroll
  for (int ct = 0; ct < 8; ++ct) {
    float bvv = bv[ct * 16 + l15];
#pragma unroll
    for (int g = 0; g < 2; ++g)
#pragma unroll
      for (int rg = 0; rg < 4; ++rg)
        V_lds[ct * 16 + l15][tt0 + g * 16 + 4 * l4 + rg] = f2bf(acc[g][ct][rg] + bvv);
  }
  __syncthreads();  // barrier 2: K/V complete
  {  // in-block vmean over V^T rows
    int d = tid >> 2, seg = tid & 3;
    const u16* vr = &V_lds[d][seg * 64];
    float s = 0.f;
#pragma unroll
    for (int j = 0; j < 8; ++j) {
      uint4 u = *(const uint4*)(vr + j * 8);
      s += bf2f((u16)(u.x & 0xffff)) + bf2f((u16)(u.x >> 16));
      s += bf2f((u16)(u.y & 0xffff)) + bf2f((u16)(u.y >> 16));
      s += bf2f((u16)(u.z & 0xffff)) + bf2f((u16)(u.z >> 16));
      s += bf2f((u16)(u.w & 0xffff)) + bf2f((u16)(u.w >> 16));
    }
    s += __shfl_xor(s, 1); s += __shfl_xor(s, 2);
    if (seg == 0) vmean_lds[d] = s * (1.f / 256.f);
  }
  float lsum[2][4]; f32x4 cacc[2][8];
#pragma unroll
  for (int g = 0; g < 2; ++g)
#pragma unroll
    for (int rg = 0; rg < 4; ++rg) lsum[g][rg] = 0.f;
#pragma unroll
  for (int g = 0; g < 2; ++g)
#pragma unroll
    for (int ct = 0; ct < 8; ++ct) cacc[g][ct] = f32x4{0.f, 0.f, 0.f, 0.f};
  __syncthreads();  // barrier 3: vmean ready; no more block syncs

  // ---- attention: fixed-max softmax, 32 rows/wave ----
  const int nkv = (wv >> 1) + 1;
  for (int kv = 0; kv < nkv; ++kv) {
    const int s0 = kv * 64;
    f32x4 sacc[2][4];
#pragma unroll
    for (int g = 0; g < 2; ++g)
#pragma unroll
      for (int ct = 0; ct < 4; ++ct) sacc[g][ct] = f32x4{0.f, 0.f, 0.f, 0.f};
#pragma unroll
    for (int ct = 0; ct < 4; ++ct)
#pragma unroll
      for (int ks = 0; ks < 4; ++ks) {
        bf16x8 bfr = *(const bf16x8*)&KX[s0 + ct * 16 + l15][ks * 32 + l4 * 8];
#pragma unroll
        for (int g = 0; g < 2; ++g) sacc[g][ct] = MFMA16(qa[g][ks], bfr, sacc[g][ct]);
      }
    int km[4];
#pragma unroll
    for (int ct = 0; ct < 4; ++ct) km[ct] = mrow[s0 + ct * 16 + l15];
    float p[2][4][4];
#pragma unroll
    for (int g = 0; g < 2; ++g)
#pragma unroll
      for (int ct = 0; ct < 4; ++ct) {
        const int ss = s0 + ct * 16 + l15;
#pragma unroll
        for (int rg = 0; rg < 4; ++rg) {
          float sv = sacc[g][ct][rg] + rel_lds[ttg[g][rg] - ss + 255];
          bool msk = (ss > ttg[g][rg]) | (km[ct] == 0) | (qm[g][rg] == 0);
          sv = msk ? -1.0e9f : sv;
          float pv = __expf(sv);  // masked -> exactly 0
          p[g][ct][rg] = pv;
          lsum[g][rg] += pv;
        }
      }
#pragma unroll
    for (int c = 0; c < 2; ++c) {
#pragma unroll
      for (int g = 0; g < 2; ++g)
#pragma unroll
        for (int c2 = 0; c2 < 2; ++c2)
#pragma unroll
          for (int rg = 0; rg < 4; ++rg)
            P_lds[wv][g * 16 + 4 * l4 + rg][c2 * 16 + l15] = f2bf(p[g][2 * c + c2][rg]);
      bf16x8 pa[2];
#pragma unroll
      for (int g = 0; g < 2; ++g)
        pa[g] = *(const bf16x8*)&P_lds[wv][g * 16 + l15][l4 * 8];
#pragma unroll
      for (int ct = 0; ct < 8; ++ct) {
        bf16x8 vb = *(const bf16x8*)&V_lds[ct * 16 + l15][s0 + c * 32 + l4 * 8];
#pragma unroll
        for (int g = 0; g < 2; ++g) cacc[g][ct] = MFMA16(pa[g], vb, cacc[g][ct]);
      }
    }
  }
  float li[2][4];
#pragma unroll
  for (int g = 0; g < 2; ++g)
#pragma unroll
    for (int rg = 0; rg < 4; ++rg) {
      float rs = lsum[g][rg];
#pragma unroll
      for (int off = 1; off < 16; off <<= 1) rs += __shfl_xor(rs, off);
      li[g][rg] = rs;
    }
  // ---- ctx -> out-proj -> residual+LN -> scatter (fused1 epilogue) ----
  bf16x8 ca[2][4];
#pragma unroll
  for (int q = 0; q < 4; ++q) {
#pragma unroll
    for (int g = 0; g < 2; ++g)
#pragma unroll
      for (int c2 = 0; c2 < 2; ++c2) {
        int ct = 2 * q + c2;
        float vm = vmean_lds[ct * 16 + l15];
#pragma unroll
        for (int rg = 0; rg < 4; ++rg) {
          float cval = cacc[g][ct][rg] / li[g][rg];
          cval = (qm[g][rg] == 0) ? vm : cval;
          P_lds[wv][g * 16 + 4 * l4 + rg][c2 * 16 + l15] = f2bf(cval);
        }
      }
#pragma unroll
    for (int g = 0; g < 2; ++g)
      ca[g][q] = *(const bf16x8*)&P_lds[wv][g * 16 + l15][l4 * 8];
  }
  f32x4 oacc[2][8];
#pragma unroll
  for (int g = 0; g < 2; ++g)
#pragma unroll
    for (int ct = 0; ct < 8; ++ct) oacc[g][ct] = f32x4{0.f, 0.f, 0.f, 0.f};
#pragma unroll
  for (int ct = 0; ct < 8; ++ct)
#pragma unroll
    for (int ks = 0; ks < 4; ++ks) {
      bf16x8 wb = *(const bf16x8*)(Wt + (size_t)(3 * 128 + ct * 16 + l15) * 128 + ks * 32 + l4 * 8);
#pragma unroll
      for (int g = 0; g < 2; ++g) oacc[g][ct] = MFMA16(ca[g][ks], wb, oacc[g][ct]);
    }
  float bpv[8], gv[8], bt[8];
#pragma unroll
  for (int ct = 0; ct < 8; ++ct) {
    int d = ct * 16 + l15;
    bpv[ct] = bp[d]; gv[ct] = ln_g[d]; bt[ct] = ln_b[d];
  }
#pragma unroll
  for (int g = 0; g < 2; ++g)
#pragma unroll
    for (int rg = 0; rg < 4; ++rg) {
      const int tg = ttg[g][rg];
      float yv[8], sum = 0.f, sq = 0.f;
#pragma unroll
      for (int ct = 0; ct < 8; ++ct) {
        uint32_t pr = xres[g][rg][ct >> 1];
        u16 xh = (ct & 1) ? (u16)(pr >> 16) : (u16)(pr & 0xffff);
        float v = oacc[g][ct][rg] + bpv[ct] + bf2f(xh);
        yv[ct] = v; sum += v; sq += v * v;
      }
#pragma unroll
      for (int off = 1; off < 16; off <<= 1) { sum += __shfl_xor(sum, off); sq += __shfl_xor(sq, off); }
      float mean = sum * (1.f / 128.f);
      float var = sq * (1.f / 128.f) - mean * mean;
      float rstd = rsqrtf(var + 1e-5f);
      float* orow = out + (((size_t)(bb * 256 + tg)) * 100 + rr) * 128;
#pragma unroll
      for (int ct = 0; ct < 8; ++ct)
        orow[ct * 16 + l15] = (yv[ct] - mean) * rstd * gv[ct] + bt[ct];
    }
}

extern "C" void kernel_launch(void* const* d_in, const int* in_sizes, int n_in,
                              void* d_out, int out_size, void* d_ws, size_t ws_size,
                              hipStream_t stream) {
  const float* x    = (const float*)d_in[0];
  const int*   mask = (const int*)d_in[1];
  const float* Wq   = (const float*)d_in[2];
  const float* bq   = (const float*)d_in[3];
  const float* Wk   = (const float*)d_in[4];
  const float* bk   = (const float*)d_in[5];
  const float* Wv   = (const float*)d_in[6];
  const float* bv   = (const float*)d_in[7];
  const float* Wp   = (const float*)d_in[8];
  const float* bp   = (const float*)d_in[9];
  const float* ln_g = (const float*)d_in[10];
  const float* ln_b = (const float*)d_in[11];
  const float* rel  = (const float*)d_in[12];
  float* out = (float*)d_out;
  u16* Wt = (u16*)d_ws;  // [4][128][128] bf16 transposed — only workspace use

  hipLaunchKernelGGL(prep_weights_kernel, dim3(4, 64), dim3(256), 0, stream, Wq, Wk, Wv, Wp, Wt);
  hipLaunchKernelGGL(fused3_kernel, dim3(400), dim3(512), 0, stream,
                     Wt, x, mask, rel, bq, bk, bv, bp, ln_g, ln_b, out);
}